// Round 15
// baseline (313.755 us; speedup 1.0000x reference)
//
#include <hip/hip_runtime.h>
#include <hip/hip_bf16.h>

#define B 4
#define S 2048
#define H 16
#define D 64
#define HID 1024

typedef __hip_bfloat16 bf16;
typedef __attribute__((ext_vector_type(8))) short bf16x8;
typedef __attribute__((ext_vector_type(4))) short bf16x4;
typedef __attribute__((ext_vector_type(4))) float f32x4;

static __device__ __forceinline__ float b2f(bf16 v) { return __bfloat162float(v); }

static __device__ __forceinline__ unsigned pkbf(float a, float b) {
    union { bf16 h; unsigned short u; } ua, ub;
    ua.h = __float2bfloat16(a);
    ub.h = __float2bfloat16(b);
    return (unsigned)ua.u | ((unsigned)ub.u << 16);
}

#define SCL 0.18033688011112042f   // 0.125 * log2(e), folded into Q at projection

// ---------------------------------------------------------------------------
// Kernel 1: QKV projection as MFMA GEMM (unchanged from R14).
// Q pre-scaled by SCL. Q,K: [B][H][S][D]; V TRANSPOSED [B][H][D][S]
// (V^T epilogue via in-LDS transpose -> coalesced stores).
// ---------------------------------------------------------------------------
#define QSTR 72
#define VTS  136

__global__ __launch_bounds__(256) void qkv_mfma_kernel(
    const float* __restrict__ x,
    const float* __restrict__ Wq, const float* __restrict__ bq,
    const float* __restrict__ Wk, const float* __restrict__ bk,
    const float* __restrict__ Wv, const float* __restrict__ bv,
    bf16* __restrict__ q, bf16* __restrict__ k, bf16* __restrict__ v)
{
    __shared__ __align__(16) char smem[36864];
    __shared__ float bs[128];
    bf16* Xs = (bf16*)smem;
    bf16* Wt = (bf16*)(smem + 128 * QSTR * 2);

    const int tid = threadIdx.x;
    const int mat = blockIdx.y >> 3;
    const int N0  = (blockIdx.y & 7) * 128;
    const int m0  = blockIdx.x * 128;

    const float* W    = (mat == 0) ? Wq : (mat == 1) ? Wk : Wv;
    const float* bias = (mat == 0) ? bq : (mat == 1) ? bk : bv;
    bf16*        dst  = (mat == 0) ? q  : (mat == 1) ? k  : v;
    const float  oscale = (mat == 0) ? SCL : 1.0f;

    #pragma unroll
    for (int i = 0; i < 8; ++i) {
        int item = i * 256 + tid;
        int row = item >> 4, f4 = item & 15;
        float4 xv = *(const float4*)&x[(size_t)(m0 + row) * D + f4 * 4];
        union { bf16 h[4]; bf16x4 v4; } u;
        u.h[0] = __float2bfloat16(xv.x); u.h[1] = __float2bfloat16(xv.y);
        u.h[2] = __float2bfloat16(xv.z); u.h[3] = __float2bfloat16(xv.w);
        *(bf16x4*)&Xs[row * QSTR + f4 * 4] = u.v4;
    }
    #pragma unroll
    for (int i = 0; i < 2; ++i) {
        int unit = i * 256 + tid;
        int n0 = (unit & 31) * 4, k0 = (unit >> 5) * 4;
        float wv[4][4];
        #pragma unroll
        for (int j = 0; j < 4; ++j) {
            float4 t = *(const float4*)&W[(size_t)(k0 + j) * HID + N0 + n0];
            wv[j][0] = t.x; wv[j][1] = t.y; wv[j][2] = t.z; wv[j][3] = t.w;
        }
        #pragma unroll
        for (int dn = 0; dn < 4; ++dn) {
            union { bf16 h[4]; bf16x4 v4; } u;
            #pragma unroll
            for (int j = 0; j < 4; ++j) u.h[j] = __float2bfloat16(wv[j][dn]);
            *(bf16x4*)&Wt[(n0 + dn) * QSTR + k0] = u.v4;
        }
    }
    if (tid < 128) bs[tid] = bias[N0 + tid];
    __syncthreads();

    const int lane = tid & 63, wave = tid >> 6;
    const int c = lane & 15, quad = lane >> 4;

    bf16x8 af[2][2];
    #pragma unroll
    for (int mg = 0; mg < 2; ++mg)
        #pragma unroll
        for (int kc = 0; kc < 2; ++kc)
            af[mg][kc] = *(const bf16x8*)&Xs[(wave * 32 + mg * 16 + c) * QSTR + kc * 32 + quad * 8];

    f32x4 acc[2][8];
    #pragma unroll
    for (int mg = 0; mg < 2; ++mg)
        #pragma unroll
        for (int ng = 0; ng < 8; ++ng)
            acc[mg][ng] = (f32x4){0.f, 0.f, 0.f, 0.f};

    #pragma unroll
    for (int ng = 0; ng < 8; ++ng) {
        bf16x8 bf0 = *(const bf16x8*)&Wt[(ng * 16 + c) * QSTR + quad * 8];
        bf16x8 bf1 = *(const bf16x8*)&Wt[(ng * 16 + c) * QSTR + 32 + quad * 8];
        #pragma unroll
        for (int mg = 0; mg < 2; ++mg) {
            acc[mg][ng] = __builtin_amdgcn_mfma_f32_16x16x32_bf16(af[mg][0], bf0, acc[mg][ng], 0, 0, 0);
            acc[mg][ng] = __builtin_amdgcn_mfma_f32_16x16x32_bf16(af[mg][1], bf1, acc[mg][ng], 0, 0, 0);
        }
    }

    if (mat == 2) {
        bf16* T = (bf16*)smem;
        __syncthreads();
        #pragma unroll
        for (int ng = 0; ng < 8; ++ng) {
            int hid_l = ng * 16 + c;
            float bb_ = bs[hid_l];
            #pragma unroll
            for (int mg = 0; mg < 2; ++mg) {
                int ss_l = wave * 32 + mg * 16 + quad * 4;
                union { bf16 h4[4]; bf16x4 v4; } u;
                #pragma unroll
                for (int r = 0; r < 4; ++r)
                    u.h4[r] = __float2bfloat16(acc[mg][ng][r] + bb_);
                *(bf16x4*)&T[hid_l * VTS + ss_l] = u.v4;
            }
        }
        __syncthreads();
        const int b_ = m0 >> 11, ss0 = m0 & (S - 1);
        #pragma unroll
        for (int pass = 0; pass < 8; ++pass) {
            int unit = pass * 256 + tid;
            int dd_l = unit >> 4, u8 = unit & 15;
            bf16x8 val = *(const bf16x8*)&T[dd_l * VTS + u8 * 8];
            int h = (N0 >> 6) + (dd_l >> 6), ddg = dd_l & 63;
            *(bf16x8*)&dst[((size_t)(b_ * H + h) * D + ddg) * S + ss0 + u8 * 8] = val;
        }
    } else {
        #pragma unroll
        for (int ng = 0; ng < 8; ++ng) {
            int n_g = N0 + ng * 16 + c;
            int h = n_g >> 6, dd = n_g & 63;
            float bb_ = bs[ng * 16 + c];
            #pragma unroll
            for (int mg = 0; mg < 2; ++mg) {
                #pragma unroll
                for (int r = 0; r < 4; ++r) {
                    int row = m0 + wave * 32 + mg * 16 + quad * 4 + r;
                    int b_ = row >> 11, ss = row & (S - 1);
                    dst[((size_t)(b_ * H + h) * S + ss) * D + dd] =
                        __float2bfloat16((acc[mg][ng][r] + bb_) * oscale);
                }
            }
        }
    }
}

// ---------------------------------------------------------------------------
// Kernel 2: flash causal attention — DIRECT-GLOBAL FRAGMENTS, barrier-free.
// R14 post-mortem: DS pipe (~58us of K/V LDS round-trip) is the bound.
// Per-wave A-frag pattern reads each K/V row exactly once -> direct global
// frag loads cost only 4x L2 redundancy (~16 TB/s, under 34.5 ceiling), and
// the XCD swizzle keeps K+V L2-resident (R11: FETCH 24.6MB). Differences vs
// R9 (which stalled): loads issue as independent batches (8 K-frags at step
// start, 8 V-frags mid-step hidden under exp2/pack), K/V frags shared by
// BOTH tile fronts, L2-resident working set. P stays in wave-private LDS.
// NO __syncthreads in the loop; DS ops/dual-step 44 -> 12.
// ---------------------------------------------------------------------------
#define BT   64
#define NT   (S / BT)   // 32
#define PST  72

__global__ __launch_bounds__(256) void flash_mfma_kernel(
    const bf16* __restrict__ qg, const bf16* __restrict__ kg,
    const bf16* __restrict__ vg, bf16* __restrict__ og)
{
    __shared__ bf16 PsB[4][16 * PST];   // per-wave P, tile B
    __shared__ bf16 PsA[4][16 * PST];   // per-wave P, tile A

    const int tid  = threadIdx.x;
    const int wave = tid >> 6;
    const int lane = tid & 63;
    const int c    = lane & 15;
    const int quad = lane >> 4;

    const int L    = (int)blockIdx.x + 16 * (int)blockIdx.y;  // 0..1023
    const int xcd  = L & 7;
    const int slot = L >> 3;
    const int pair = slot & 15;
    const int bh   = xcd * 8 + (slot >> 4);
    const int b_   = bh >> 4, h_ = bh & 15;
    const size_t hbase = (size_t)bh * S * D;
    bf16* myPB = &PsB[wave][0];
    bf16* myPA = &PsA[wave][0];
    const int srow = wave * 16 + c;

    const int qta = pair;
    const int qtb = NT - 1 - pair;

    bf16x8 qfa0, qfa1, qfb0, qfb1;
    {
        const size_t ra = hbase + (size_t)(qta * BT + srow) * D;
        const size_t rb = hbase + (size_t)(qtb * BT + srow) * D;
        qfa0 = *(const bf16x8*)(qg + ra + quad * 8);
        qfa1 = *(const bf16x8*)(qg + ra + 32 + quad * 8);
        qfb0 = *(const bf16x8*)(qg + rb + quad * 8);
        qfb1 = *(const bf16x8*)(qg + rb + 32 + quad * 8);
    }

    // per-lane base pointers for K rows (jn*16+c) and V^T rows (jn*16+c)
    const bf16* kbase = kg + hbase + (size_t)c * D + quad * 8;
    const bf16* vbase = vg + hbase + (size_t)c * S + quad * 8;

    float la = 0.f, lb = 0.f;
    f32x4 ota[4], otb[4];
    #pragma unroll
    for (int jn = 0; jn < 4; ++jn) {
        ota[jn] = (f32x4){0.f, 0.f, 0.f, 0.f};
        otb[jn] = (f32x4){0.f, 0.f, 0.f, 0.f};
    }

    for (int kt = 0; kt <= qtb; ++kt) {
        const bool withA = (kt <= qta);   // wave-uniform

        // ---- K fragments: 8 independent global loads (L2-resident) ----
        bf16x8 kf[4][2];
        {
            const bf16* kp = kbase + (size_t)(kt * BT) * D;
            #pragma unroll
            for (int jn = 0; jn < 4; ++jn) {
                kf[jn][0] = *(const bf16x8*)(kp + (size_t)(jn * 16) * D);
                kf[jn][1] = *(const bf16x8*)(kp + (size_t)(jn * 16) * D + 32);
            }
        }

        // ---- S^T = K.Q^T, both fronts share kf ----
        f32x4 stB[4], stA[4];
        #pragma unroll
        for (int jn = 0; jn < 4; ++jn) {
            f32x4 s = {0.f, 0.f, 0.f, 0.f};
            s = __builtin_amdgcn_mfma_f32_16x16x32_bf16(kf[jn][0], qfb0, s, 0, 0, 0);
            s = __builtin_amdgcn_mfma_f32_16x16x32_bf16(kf[jn][1], qfb1, s, 0, 0, 0);
            stB[jn] = s;
            if (withA) {
                f32x4 t = {0.f, 0.f, 0.f, 0.f};
                t = __builtin_amdgcn_mfma_f32_16x16x32_bf16(kf[jn][0], qfa0, t, 0, 0, 0);
                t = __builtin_amdgcn_mfma_f32_16x16x32_bf16(kf[jn][1], qfa1, t, 0, 0, 0);
                stA[jn] = t;
            }
        }

        // ---- V fragments: issue now, consumed after softmax (latency hidden) ----
        bf16x8 vf[4][2];
        {
            const bf16* vp = vbase + kt * BT;
            #pragma unroll
            for (int jn = 0; jn < 4; ++jn) {
                vf[jn][0] = *(const bf16x8*)(vp + (size_t)(jn * 16) * S);
                vf[jn][1] = *(const bf16x8*)(vp + (size_t)(jn * 16) * S + 32);
            }
        }

        // ---- no-max exp2 softmax + P pack/write, front B ----
        #pragma unroll
        for (int jn = 0; jn < 4; ++jn) {
            float p0 = __builtin_amdgcn_exp2f(stB[jn][0]);
            float p1 = __builtin_amdgcn_exp2f(stB[jn][1]);
            float p2 = __builtin_amdgcn_exp2f(stB[jn][2]);
            float p3 = __builtin_amdgcn_exp2f(stB[jn][3]);
            if (kt == qtb) {
                int col = jn * 16 + quad * 4;
                if (col     > srow) p0 = 0.f;
                if (col + 1 > srow) p1 = 0.f;
                if (col + 2 > srow) p2 = 0.f;
                if (col + 3 > srow) p3 = 0.f;
            }
            lb += (p0 + p1) + (p2 + p3);
            uint2 pk;
            pk.x = pkbf(p0, p1);
            pk.y = pkbf(p2, p3);
            *(uint2*)&myPB[c * PST + jn * 16 + quad * 4] = pk;
        }
        // ---- front A ----
        if (withA) {
            #pragma unroll
            for (int jn = 0; jn < 4; ++jn) {
                float p0 = __builtin_amdgcn_exp2f(stA[jn][0]);
                float p1 = __builtin_amdgcn_exp2f(stA[jn][1]);
                float p2 = __builtin_amdgcn_exp2f(stA[jn][2]);
                float p3 = __builtin_amdgcn_exp2f(stA[jn][3]);
                if (kt == qta) {
                    int col = jn * 16 + quad * 4;
                    if (col     > srow) p0 = 0.f;
                    if (col + 1 > srow) p1 = 0.f;
                    if (col + 2 > srow) p2 = 0.f;
                    if (col + 3 > srow) p3 = 0.f;
                }
                la += (p0 + p1) + (p2 + p3);
                uint2 pk;
                pk.x = pkbf(p0, p1);
                pk.y = pkbf(p2, p3);
                *(uint2*)&myPA[c * PST + jn * 16 + quad * 4] = pk;
            }
        }

        asm volatile("s_waitcnt lgkmcnt(0)" ::: "memory");  // P writes visible

        // ---- O^T += V^T.P^T, both fronts share vf ----
        #pragma unroll
        for (int kc = 0; kc < 2; ++kc) {
            bf16x8 pfB = *(const bf16x8*)&myPB[c * PST + kc * 32 + quad * 8];
            bf16x8 pfA;
            if (withA) pfA = *(const bf16x8*)&myPA[c * PST + kc * 32 + quad * 8];
            #pragma unroll
            for (int jn = 0; jn < 4; ++jn) {
                otb[jn] = __builtin_amdgcn_mfma_f32_16x16x32_bf16(vf[jn][kc], pfB, otb[jn], 0, 0, 0);
                if (withA)
                    ota[jn] = __builtin_amdgcn_mfma_f32_16x16x32_bf16(vf[jn][kc], pfA, ota[jn], 0, 0, 0);
            }
        }
    }

    // ---- epilogues: single deferred cross-quad l reduction per tile ----
    {
        float lt = lb;
        lt += __shfl_xor(lt, 16);
        lt += __shfl_xor(lt, 32);
        const float inv = 1.f / lt;
        const size_t obase = ((size_t)(b_ * S + qtb * BT + srow)) * HID + h_ * 64 + quad * 4;
        #pragma unroll
        for (int jn = 0; jn < 4; ++jn) {
            union { bf16 h4[4]; bf16x4 v4; } u;
            #pragma unroll
            for (int r = 0; r < 4; ++r)
                u.h4[r] = __float2bfloat16(otb[jn][r] * inv);
            *(bf16x4*)&og[obase + jn * 16] = u.v4;
        }
    }
    {
        float lt = la;
        lt += __shfl_xor(lt, 16);
        lt += __shfl_xor(lt, 32);
        const float inv = 1.f / lt;
        const size_t obase = ((size_t)(b_ * S + qta * BT + srow)) * HID + h_ * 64 + quad * 4;
        #pragma unroll
        for (int jn = 0; jn < 4; ++jn) {
            union { bf16 h4[4]; bf16x4 v4; } u;
            #pragma unroll
            for (int r = 0; r < 4; ++r)
                u.h4[r] = __float2bfloat16(ota[jn][r] * inv);
            *(bf16x4*)&og[obase + jn * 16] = u.v4;
        }
    }
}

// ---------------------------------------------------------------------------
// Kernel 3: output projection as MFMA GEMM, 32-row tiles, grid 256,
// NEW (R15): register prefetch of next chunk's o-tile + Wo-tile (R8 pattern).
// ---------------------------------------------------------------------------
__global__ __launch_bounds__(256) void out_proj_mfma_kernel(
    const bf16* __restrict__ o, const float* __restrict__ Wo,
    const float* __restrict__ bo, float* __restrict__ out)
{
    __shared__ bf16 Os[32 * QSTR];
    __shared__ bf16 Wot[64 * QSTR];
    __shared__ float bos[64];

    const int tid = threadIdx.x;
    const int m0  = blockIdx.x * 32;
    const int lane = tid & 63, wave = tid >> 6;
    const int c = lane & 15, quad = lane >> 4;
    const int mtile = wave >> 1;
    const int ngb   = (wave & 1) * 2;

    const int orow = tid >> 3, ooct = tid & 7;
    const int n0 = (tid & 15) * 4, kk0 = (tid >> 4) * 4;

    if (tid < 64) bos[tid] = bo[tid];

    // prefetch chunk 0
    bf16x8 oreg = *(const bf16x8*)(o + (size_t)(m0 + orow) * HID + ooct * 8);
    float4 w4[4];
    #pragma unroll
    for (int j = 0; j < 4; ++j)
        w4[j] = *(const float4*)&Wo[(size_t)(kk0 + j) * 64 + n0];

    f32x4 acc[2];
    acc[0] = (f32x4){0.f, 0.f, 0.f, 0.f};
    acc[1] = (f32x4){0.f, 0.f, 0.f, 0.f};

    for (int chunk = 0; chunk < 16; ++chunk) {
        __syncthreads();
        *(bf16x8*)&Os[orow * QSTR + ooct * 8] = oreg;
        #pragma unroll
        for (int dn = 0; dn < 4; ++dn) {
            union { bf16 h[4]; bf16x4 v4; } u;
            u.h[0] = __float2bfloat16((&w4[0].x)[dn]);
            u.h[1] = __float2bfloat16((&w4[1].x)[dn]);
            u.h[2] = __float2bfloat16((&w4[2].x)[dn]);
            u.h[3] = __float2bfloat16((&w4[3].x)[dn]);
            *(bf16x4*)&Wot[(n0 + dn) * QSTR + kk0] = u.v4;
        }
        __syncthreads();

        if (chunk < 15) {
            const int k1 = (chunk + 1) * 64;
            oreg = *(const bf16x8*)(o + (size_t)(m0 + orow) * HID + k1 + ooct * 8);
            #pragma unroll
            for (int j = 0; j < 4; ++j)
                w4[j] = *(const float4*)&Wo[(size_t)(k1 + kk0 + j) * 64 + n0];
        }

        bf16x8 a0 = *(const bf16x8*)&Os[(mtile * 16 + c) * QSTR + quad * 8];
        bf16x8 a1 = *(const bf16x8*)&Os[(mtile * 16 + c) * QSTR + 32 + quad * 8];
        #pragma unroll
        for (int g = 0; g < 2; ++g) {
            int ng = ngb + g;
            bf16x8 b0 = *(const bf16x8*)&Wot[(ng * 16 + c) * QSTR + quad * 8];
            bf16x8 b1 = *(const bf16x8*)&Wot[(ng * 16 + c) * QSTR + 32 + quad * 8];
            acc[g] = __builtin_amdgcn_mfma_f32_16x16x32_bf16(a0, b0, acc[g], 0, 0, 0);
            acc[g] = __builtin_amdgcn_mfma_f32_16x16x32_bf16(a1, b1, acc[g], 0, 0, 0);
        }
    }

    #pragma unroll
    for (int g = 0; g < 2; ++g) {
        int n = (ngb + g) * 16 + c;
        float bb_ = bos[n];
        #pragma unroll
        for (int r = 0; r < 4; ++r) {
            int row = m0 + mtile * 16 + quad * 4 + r;
            out[(size_t)row * 64 + n] = acc[g][r] + bb_;
        }
    }
}

// ---------------------------------------------------------------------------
extern "C" void kernel_launch(void* const* d_in, const int* in_sizes, int n_in,
                              void* d_out, int out_size, void* d_ws, size_t ws_size,
                              hipStream_t stream)
{
    const float* x  = (const float*)d_in[0];
    const float* Wq = (const float*)d_in[1];
    const float* bq = (const float*)d_in[2];
    const float* Wk = (const float*)d_in[3];
    const float* bk = (const float*)d_in[4];
    const float* Wv = (const float*)d_in[5];
    const float* bv = (const float*)d_in[6];
    const float* Wo = (const float*)d_in[7];
    const float* bo = (const float*)d_in[8];

    char* ws = (char*)d_ws;
    const size_t qkv_bytes = (size_t)B * S * HID * sizeof(bf16);  // 16 MiB each
    bf16* qw = (bf16*)(ws);
    bf16* kw = (bf16*)(ws + qkv_bytes);
    bf16* vw = (bf16*)(ws + 2 * qkv_bytes);   // transposed [B][H][D][S]
    bf16* ow = (bf16*)(ws + 3 * qkv_bytes);

    qkv_mfma_kernel<<<dim3(B * S / 128, 24), 256, 0, stream>>>(
        x, Wq, bq, Wk, bk, Wv, bv, qw, kw, vw);

    flash_mfma_kernel<<<dim3(NT / 2, B * H), 256, 0, stream>>>(qw, kw, vw, ow);

    out_proj_mfma_kernel<<<dim3(B * S / 32), 256, 0, stream>>>(ow, Wo, bo,
                                                               (float*)d_out);
}

// Round 16
// 172.375 us; speedup vs baseline: 1.8202x; 1.8202x over previous
//
#include <hip/hip_runtime.h>
#include <hip/hip_bf16.h>

#define B 4
#define S 2048
#define H 16
#define D 64
#define HID 1024

typedef __hip_bfloat16 bf16;
typedef __attribute__((ext_vector_type(8))) short bf16x8;
typedef __attribute__((ext_vector_type(4))) short bf16x4;
typedef __attribute__((ext_vector_type(4))) float f32x4;

static __device__ __forceinline__ float b2f(bf16 v) { return __bfloat162float(v); }

static __device__ __forceinline__ unsigned pkbf(float a, float b) {
    union { bf16 h; unsigned short u; } ua, ub;
    ua.h = __float2bfloat16(a);
    ub.h = __float2bfloat16(b);
    return (unsigned)ua.u | ((unsigned)ub.u << 16);
}

#define SCL 0.18033688011112042f   // 0.125 * log2(e), folded into Q at projection

// ---------------------------------------------------------------------------
// Kernel 1: QKV projection as MFMA GEMM.
// Q pre-scaled by SCL. Q,K: [B][H][S][D]; V TRANSPOSED [B][H][D][S].
// NEW (R16): Q/K epilogue also routed through in-LDS repack T2[row][n]
// -> b128 coalesced stores (was 64 scalar 2B stores/thread in 32B segments,
// the same write-amplification disease V had before R14).
// ---------------------------------------------------------------------------
#define QSTR 72
#define VTS  132   // repack stride: (VTS/2)%4 != 0 -> quad rows hit disjoint banks

__global__ __launch_bounds__(256) void qkv_mfma_kernel(
    const float* __restrict__ x,
    const float* __restrict__ Wq, const float* __restrict__ bq,
    const float* __restrict__ Wk, const float* __restrict__ bk,
    const float* __restrict__ Wv, const float* __restrict__ bv,
    bf16* __restrict__ q, bf16* __restrict__ k, bf16* __restrict__ v)
{
    __shared__ __align__(16) char smem[36864];  // Xs+Wt; reused for repack
    __shared__ float bs[128];
    bf16* Xs = (bf16*)smem;
    bf16* Wt = (bf16*)(smem + 128 * QSTR * 2);

    const int tid = threadIdx.x;
    const int mat = blockIdx.y >> 3;
    const int N0  = (blockIdx.y & 7) * 128;
    const int m0  = blockIdx.x * 128;

    const float* W    = (mat == 0) ? Wq : (mat == 1) ? Wk : Wv;
    const float* bias = (mat == 0) ? bq : (mat == 1) ? bk : bv;
    bf16*        dst  = (mat == 0) ? q  : (mat == 1) ? k  : v;
    const float  oscale = (mat == 0) ? SCL : 1.0f;

    #pragma unroll
    for (int i = 0; i < 8; ++i) {
        int item = i * 256 + tid;
        int row = item >> 4, f4 = item & 15;
        float4 xv = *(const float4*)&x[(size_t)(m0 + row) * D + f4 * 4];
        union { bf16 h[4]; bf16x4 v4; } u;
        u.h[0] = __float2bfloat16(xv.x); u.h[1] = __float2bfloat16(xv.y);
        u.h[2] = __float2bfloat16(xv.z); u.h[3] = __float2bfloat16(xv.w);
        *(bf16x4*)&Xs[row * QSTR + f4 * 4] = u.v4;
    }
    #pragma unroll
    for (int i = 0; i < 2; ++i) {
        int unit = i * 256 + tid;
        int n0 = (unit & 31) * 4, k0 = (unit >> 5) * 4;
        float wv[4][4];
        #pragma unroll
        for (int j = 0; j < 4; ++j) {
            float4 t = *(const float4*)&W[(size_t)(k0 + j) * HID + N0 + n0];
            wv[j][0] = t.x; wv[j][1] = t.y; wv[j][2] = t.z; wv[j][3] = t.w;
        }
        #pragma unroll
        for (int dn = 0; dn < 4; ++dn) {
            union { bf16 h[4]; bf16x4 v4; } u;
            #pragma unroll
            for (int j = 0; j < 4; ++j) u.h[j] = __float2bfloat16(wv[j][dn]);
            *(bf16x4*)&Wt[(n0 + dn) * QSTR + k0] = u.v4;
        }
    }
    if (tid < 128) bs[tid] = bias[N0 + tid];
    __syncthreads();

    const int lane = tid & 63, wave = tid >> 6;
    const int c = lane & 15, quad = lane >> 4;

    bf16x8 af[2][2];
    #pragma unroll
    for (int mg = 0; mg < 2; ++mg)
        #pragma unroll
        for (int kc = 0; kc < 2; ++kc)
            af[mg][kc] = *(const bf16x8*)&Xs[(wave * 32 + mg * 16 + c) * QSTR + kc * 32 + quad * 8];

    f32x4 acc[2][8];
    #pragma unroll
    for (int mg = 0; mg < 2; ++mg)
        #pragma unroll
        for (int ng = 0; ng < 8; ++ng)
            acc[mg][ng] = (f32x4){0.f, 0.f, 0.f, 0.f};

    #pragma unroll
    for (int ng = 0; ng < 8; ++ng) {
        bf16x8 bf0 = *(const bf16x8*)&Wt[(ng * 16 + c) * QSTR + quad * 8];
        bf16x8 bf1 = *(const bf16x8*)&Wt[(ng * 16 + c) * QSTR + 32 + quad * 8];
        #pragma unroll
        for (int mg = 0; mg < 2; ++mg) {
            acc[mg][ng] = __builtin_amdgcn_mfma_f32_16x16x32_bf16(af[mg][0], bf0, acc[mg][ng], 0, 0, 0);
            acc[mg][ng] = __builtin_amdgcn_mfma_f32_16x16x32_bf16(af[mg][1], bf1, acc[mg][ng], 0, 0, 0);
        }
    }

    if (mat == 2) {
        // ---- V: in-LDS transpose T[hid][ss] -> coalesced [B][H][D][S] ----
        bf16* T = (bf16*)smem;            // 128 x VTS bf16
        __syncthreads();
        #pragma unroll
        for (int ng = 0; ng < 8; ++ng) {
            int hid_l = ng * 16 + c;
            float bb_ = bs[hid_l];
            #pragma unroll
            for (int mg = 0; mg < 2; ++mg) {
                int ss_l = wave * 32 + mg * 16 + quad * 4;
                union { bf16 h4[4]; bf16x4 v4; } u;
                #pragma unroll
                for (int r = 0; r < 4; ++r)
                    u.h4[r] = __float2bfloat16(acc[mg][ng][r] + bb_);
                *(bf16x4*)&T[hid_l * VTS + ss_l] = u.v4;
            }
        }
        __syncthreads();
        const int b_ = m0 >> 11, ss0 = m0 & (S - 1);
        #pragma unroll
        for (int pass = 0; pass < 8; ++pass) {
            int unit = pass * 256 + tid;
            int dd_l = unit >> 4, u8 = unit & 15;
            bf16x8 val = *(const bf16x8*)&T[dd_l * VTS + u8 * 8];
            int h = (N0 >> 6) + (dd_l >> 6), ddg = dd_l & 63;
            *(bf16x8*)&dst[((size_t)(b_ * H + h) * D + ddg) * S + ss0 + u8 * 8] = val;
        }
    } else {
        // ---- Q/K: in-LDS repack T2[row][n] -> coalesced [B][H][S][D] ----
        bf16* T2 = (bf16*)smem;           // 128 x VTS bf16
        __syncthreads();
        #pragma unroll
        for (int ng = 0; ng < 8; ++ng) {
            int n_l = ng * 16 + c;
            float bb_ = bs[n_l];
            #pragma unroll
            for (int mg = 0; mg < 2; ++mg) {
                int row0 = wave * 32 + mg * 16 + quad * 4;
                #pragma unroll
                for (int r = 0; r < 4; ++r)
                    T2[(row0 + r) * VTS + n_l] =
                        __float2bfloat16((acc[mg][ng][r] + bb_) * oscale);
            }
        }
        __syncthreads();
        const int b_ = m0 >> 11, ss0 = m0 & (S - 1);
        #pragma unroll
        for (int pass = 0; pass < 8; ++pass) {
            int unit = pass * 256 + tid;
            int row_l = unit >> 4, n8 = unit & 15;
            bf16x8 val = *(const bf16x8*)&T2[row_l * VTS + n8 * 8];
            int n_g = N0 + n8 * 8;
            int h = n_g >> 6, dd = n_g & 63;
            *(bf16x8*)&dst[((size_t)(b_ * H + h) * S + ss0 + row_l) * D + dd] = val;
        }
    }
}

// ---------------------------------------------------------------------------
// Kernel 2: flash causal attention — EXACT R14 kernel (82.3us proven).
// R15 post-mortem: direct-global MFMA operands stall on the vmcnt drain even
// when L2-resident (FETCH 24.6MB yet VALUBusy 42->23%). THIRD confirmation
// (R9, R15): MFMA operands must come from LDS via the prefetch-reg pipeline.
// ---------------------------------------------------------------------------
#define BT   64
#define NT   (S / BT)   // 32
#define KSTR 72
#define PST  72

__global__ __launch_bounds__(256) void flash_mfma_kernel(
    const bf16* __restrict__ qg, const bf16* __restrict__ kg,
    const bf16* __restrict__ vg, bf16* __restrict__ og)
{
    __shared__ bf16 Ks[BT * KSTR];      // K tile [krow][d]
    __shared__ bf16 Vt[BT * KSTR];      // V^T tile [d][krow]
    __shared__ bf16 PsB[4][16 * PST];   // per-wave P, tile B
    __shared__ bf16 PsA[4][16 * PST];   // per-wave P, tile A

    const int tid  = threadIdx.x;
    const int wave = tid >> 6;
    const int lane = tid & 63;
    const int c    = lane & 15;
    const int quad = lane >> 4;

    const int L    = (int)blockIdx.x + 16 * (int)blockIdx.y;  // 0..1023
    const int xcd  = L & 7;
    const int slot = L >> 3;
    const int pair = slot & 15;
    const int bh   = xcd * 8 + (slot >> 4);
    const int b_   = bh >> 4, h_ = bh & 15;
    const size_t hbase = (size_t)bh * S * D;
    bf16* myPB = &PsB[wave][0];
    bf16* myPA = &PsA[wave][0];
    const int srow = wave * 16 + c;

    const int qta = pair;
    const int qtb = NT - 1 - pair;

    const int sr0 = tid >> 3,         sc0 = (tid & 7) * 8;
    const int sr1 = (tid + 256) >> 3, sc1 = sc0;

    bf16x8 qfa0, qfa1, qfb0, qfb1;
    {
        const size_t ra = hbase + (size_t)(qta * BT + srow) * D;
        const size_t rb = hbase + (size_t)(qtb * BT + srow) * D;
        qfa0 = *(const bf16x8*)(qg + ra + quad * 8);
        qfa1 = *(const bf16x8*)(qg + ra + 32 + quad * 8);
        qfb0 = *(const bf16x8*)(qg + rb + quad * 8);
        qfb1 = *(const bf16x8*)(qg + rb + 32 + quad * 8);
    }

    bf16x8 kreg0, kreg1, vreg0, vreg1;
    kreg0 = *(const bf16x8*)(kg + hbase + (size_t)sr0 * D + sc0);
    kreg1 = *(const bf16x8*)(kg + hbase + (size_t)sr1 * D + sc1);
    vreg0 = *(const bf16x8*)(vg + hbase + (size_t)sr0 * S + sc0);
    vreg1 = *(const bf16x8*)(vg + hbase + (size_t)sr1 * S + sc1);

    float la = 0.f, lb = 0.f;
    f32x4 ota[4], otb[4];
    #pragma unroll
    for (int jn = 0; jn < 4; ++jn) {
        ota[jn] = (f32x4){0.f, 0.f, 0.f, 0.f};
        otb[jn] = (f32x4){0.f, 0.f, 0.f, 0.f};
    }

    auto front = [&](bf16x8 qf0, bf16x8 qf1, bf16* Pdst, float& l1, bool diag) {
        f32x4 st[4];
        #pragma unroll
        for (int jn = 0; jn < 4; ++jn) {
            bf16x8 kf0 = *(const bf16x8*)&Ks[(jn * 16 + c) * KSTR + quad * 8];
            bf16x8 kf1 = *(const bf16x8*)&Ks[(jn * 16 + c) * KSTR + 32 + quad * 8];
            f32x4 s = {0.f, 0.f, 0.f, 0.f};
            s = __builtin_amdgcn_mfma_f32_16x16x32_bf16(kf0, qf0, s, 0, 0, 0);
            s = __builtin_amdgcn_mfma_f32_16x16x32_bf16(kf1, qf1, s, 0, 0, 0);
            st[jn] = s;
        }
        #pragma unroll
        for (int jn = 0; jn < 4; ++jn) {
            float p0 = __builtin_amdgcn_exp2f(st[jn][0]);
            float p1 = __builtin_amdgcn_exp2f(st[jn][1]);
            float p2 = __builtin_amdgcn_exp2f(st[jn][2]);
            float p3 = __builtin_amdgcn_exp2f(st[jn][3]);
            if (diag) {
                int col = jn * 16 + quad * 4;
                if (col     > srow) p0 = 0.f;
                if (col + 1 > srow) p1 = 0.f;
                if (col + 2 > srow) p2 = 0.f;
                if (col + 3 > srow) p3 = 0.f;
            }
            l1 += (p0 + p1) + (p2 + p3);
            uint2 pk;
            pk.x = pkbf(p0, p1);
            pk.y = pkbf(p2, p3);
            *(uint2*)&Pdst[c * PST + jn * 16 + quad * 4] = pk;
        }
    };
    auto pv = [&](const bf16* Psrc, f32x4* ot) {
        #pragma unroll
        for (int kc = 0; kc < 2; ++kc) {
            bf16x8 pf = *(const bf16x8*)&Psrc[c * PST + kc * 32 + quad * 8];
            #pragma unroll
            for (int jn = 0; jn < 4; ++jn) {
                bf16x8 vf = *(const bf16x8*)&Vt[(jn * 16 + c) * KSTR + kc * 32 + quad * 8];
                ot[jn] = __builtin_amdgcn_mfma_f32_16x16x32_bf16(vf, pf, ot[jn], 0, 0, 0);
            }
        }
    };

    for (int kt = 0; kt <= qtb; ++kt) {
        __syncthreads();
        *(bf16x8*)&Ks[sr0 * KSTR + sc0] = kreg0;
        *(bf16x8*)&Ks[sr1 * KSTR + sc1] = kreg1;
        *(bf16x8*)&Vt[sr0 * KSTR + sc0] = vreg0;
        *(bf16x8*)&Vt[sr1 * KSTR + sc1] = vreg1;
        __syncthreads();

        if (kt < qtb) {
            const int nb = (kt + 1) * BT;
            kreg0 = *(const bf16x8*)(kg + hbase + (size_t)(nb + sr0) * D + sc0);
            kreg1 = *(const bf16x8*)(kg + hbase + (size_t)(nb + sr1) * D + sc1);
            vreg0 = *(const bf16x8*)(vg + hbase + (size_t)sr0 * S + nb + sc0);
            vreg1 = *(const bf16x8*)(vg + hbase + (size_t)sr1 * S + nb + sc1);
        }

        const bool withA = (kt <= qta);   // wave-uniform
        front(qfb0, qfb1, myPB, lb, kt == qtb);
        if (withA) front(qfa0, qfa1, myPA, la, kt == qta);
        asm volatile("s_waitcnt lgkmcnt(0)" ::: "memory");  // P writes visible
        pv(myPB, otb);
        if (withA) pv(myPA, ota);
    }

    {
        float lt = lb;
        lt += __shfl_xor(lt, 16);
        lt += __shfl_xor(lt, 32);
        const float inv = 1.f / lt;
        const size_t obase = ((size_t)(b_ * S + qtb * BT + srow)) * HID + h_ * 64 + quad * 4;
        #pragma unroll
        for (int jn = 0; jn < 4; ++jn) {
            union { bf16 h4[4]; bf16x4 v4; } u;
            #pragma unroll
            for (int r = 0; r < 4; ++r)
                u.h4[r] = __float2bfloat16(otb[jn][r] * inv);
            *(bf16x4*)&og[obase + jn * 16] = u.v4;
        }
    }
    {
        float lt = la;
        lt += __shfl_xor(lt, 16);
        lt += __shfl_xor(lt, 32);
        const float inv = 1.f / lt;
        const size_t obase = ((size_t)(b_ * S + qta * BT + srow)) * HID + h_ * 64 + quad * 4;
        #pragma unroll
        for (int jn = 0; jn < 4; ++jn) {
            union { bf16 h4[4]; bf16x4 v4; } u;
            #pragma unroll
            for (int r = 0; r < 4; ++r)
                u.h4[r] = __float2bfloat16(ota[jn][r] * inv);
            *(bf16x4*)&og[obase + jn * 16] = u.v4;
        }
    }
}

// ---------------------------------------------------------------------------
// Kernel 3: output projection as MFMA GEMM, 32-row tiles, grid 256,
// register prefetch of next chunk (R15 version, kept).
// ---------------------------------------------------------------------------
__global__ __launch_bounds__(256) void out_proj_mfma_kernel(
    const bf16* __restrict__ o, const float* __restrict__ Wo,
    const float* __restrict__ bo, float* __restrict__ out)
{
    __shared__ bf16 Os[32 * QSTR];
    __shared__ bf16 Wot[64 * QSTR];
    __shared__ float bos[64];

    const int tid = threadIdx.x;
    const int m0  = blockIdx.x * 32;
    const int lane = tid & 63, wave = tid >> 6;
    const int c = lane & 15, quad = lane >> 4;
    const int mtile = wave >> 1;
    const int ngb   = (wave & 1) * 2;

    const int orow = tid >> 3, ooct = tid & 7;
    const int n0 = (tid & 15) * 4, kk0 = (tid >> 4) * 4;

    if (tid < 64) bos[tid] = bo[tid];

    bf16x8 oreg = *(const bf16x8*)(o + (size_t)(m0 + orow) * HID + ooct * 8);
    float4 w4[4];
    #pragma unroll
    for (int j = 0; j < 4; ++j)
        w4[j] = *(const float4*)&Wo[(size_t)(kk0 + j) * 64 + n0];

    f32x4 acc[2];
    acc[0] = (f32x4){0.f, 0.f, 0.f, 0.f};
    acc[1] = (f32x4){0.f, 0.f, 0.f, 0.f};

    for (int chunk = 0; chunk < 16; ++chunk) {
        __syncthreads();
        *(bf16x8*)&Os[orow * QSTR + ooct * 8] = oreg;
        #pragma unroll
        for (int dn = 0; dn < 4; ++dn) {
            union { bf16 h[4]; bf16x4 v4; } u;
            u.h[0] = __float2bfloat16((&w4[0].x)[dn]);
            u.h[1] = __float2bfloat16((&w4[1].x)[dn]);
            u.h[2] = __float2bfloat16((&w4[2].x)[dn]);
            u.h[3] = __float2bfloat16((&w4[3].x)[dn]);
            *(bf16x4*)&Wot[(n0 + dn) * QSTR + kk0] = u.v4;
        }
        __syncthreads();

        if (chunk < 15) {
            const int k1 = (chunk + 1) * 64;
            oreg = *(const bf16x8*)(o + (size_t)(m0 + orow) * HID + k1 + ooct * 8);
            #pragma unroll
            for (int j = 0; j < 4; ++j)
                w4[j] = *(const float4*)&Wo[(size_t)(k1 + kk0 + j) * 64 + n0];
        }

        bf16x8 a0 = *(const bf16x8*)&Os[(mtile * 16 + c) * QSTR + quad * 8];
        bf16x8 a1 = *(const bf16x8*)&Os[(mtile * 16 + c) * QSTR + 32 + quad * 8];
        #pragma unroll
        for (int g = 0; g < 2; ++g) {
            int ng = ngb + g;
            bf16x8 b0 = *(const bf16x8*)&Wot[(ng * 16 + c) * QSTR + quad * 8];
            bf16x8 b1 = *(const bf16x8*)&Wot[(ng * 16 + c) * QSTR + 32 + quad * 8];
            acc[g] = __builtin_amdgcn_mfma_f32_16x16x32_bf16(a0, b0, acc[g], 0, 0, 0);
            acc[g] = __builtin_amdgcn_mfma_f32_16x16x32_bf16(a1, b1, acc[g], 0, 0, 0);
        }
    }

    #pragma unroll
    for (int g = 0; g < 2; ++g) {
        int n = (ngb + g) * 16 + c;
        float bb_ = bos[n];
        #pragma unroll
        for (int r = 0; r < 4; ++r) {
            int row = m0 + mtile * 16 + quad * 4 + r;
            out[(size_t)row * 64 + n] = acc[g][r] + bb_;
        }
    }
}

// ---------------------------------------------------------------------------
extern "C" void kernel_launch(void* const* d_in, const int* in_sizes, int n_in,
                              void* d_out, int out_size, void* d_ws, size_t ws_size,
                              hipStream_t stream)
{
    const float* x  = (const float*)d_in[0];
    const float* Wq = (const float*)d_in[1];
    const float* bq = (const float*)d_in[2];
    const float* Wk = (const float*)d_in[3];
    const float* bk = (const float*)d_in[4];
    const float* Wv = (const float*)d_in[5];
    const float* bv = (const float*)d_in[6];
    const float* Wo = (const float*)d_in[7];
    const float* bo = (const float*)d_in[8];

    char* ws = (char*)d_ws;
    const size_t qkv_bytes = (size_t)B * S * HID * sizeof(bf16);  // 16 MiB each
    bf16* qw = (bf16*)(ws);
    bf16* kw = (bf16*)(ws + qkv_bytes);
    bf16* vw = (bf16*)(ws + 2 * qkv_bytes);   // transposed [B][H][D][S]
    bf16* ow = (bf16*)(ws + 3 * qkv_bytes);

    qkv_mfma_kernel<<<dim3(B * S / 128, 24), 256, 0, stream>>>(
        x, Wq, bq, Wk, bk, Wv, bv, qw, kw, vw);

    flash_mfma_kernel<<<dim3(NT / 2, B * H), 256, 0, stream>>>(qw, kw, vw, ow);

    out_proj_mfma_kernel<<<dim3(B * S / 32), 256, 0, stream>>>(ow, Wo, bo,
                                                               (float*)d_out);
}